// Round 6
// baseline (96.439 us; speedup 1.0000x reference)
//
#include <hip/hip_runtime.h>

// NestedFormula: DEPTH=4, V=4, B=131072. n1=125, n2=25, n3=5, n4=1.
//
// R4 structure (best measured): 4-way tree split across blockIdx.y = r
// (wave-uniform -> zero divergence, params on the scalar pipe), fp32
// atomics into zeroed out. 2048 blocks, 8192 waves.
//
// R6 change: all (n,4) param rows loaded as float4 -> s_load_dwordx4 (+
// adjacent-row merging to x8/x16). Theory: R2/R4 both sat ~3x above the
// VALU+trans floor at very different occupancies => bottleneck is the
// per-CU scalar-memory issue pipe (~2 s_load/term/wave x 32 waves vs
// ~1 issue/cyc). float4 rows cut SMEM issues ~4-8x.

#define VV 4

__device__ __forceinline__ float f1_eval(int n1, const float lx[VV],
    const float* __restrict__ lam0, const float4* __restrict__ lam1,
    const float4* __restrict__ pow1)
{
    const float4 L = lam1[n1];
    const float4 P = pow1[n1];
    float e0 = __builtin_amdgcn_exp2f(P.x * lx[0]);
    float e1 = __builtin_amdgcn_exp2f(P.y * lx[1]);
    float e2 = __builtin_amdgcn_exp2f(P.z * lx[2]);
    float e3 = __builtin_amdgcn_exp2f(P.w * lx[3]);
    float s0 = fmaf(L.y, e1, fmaf(L.x, e0, lam0[n1]));
    float s1 = fmaf(L.w, e3, L.z * e2);
    return s0 + s1;
}

__device__ __forceinline__ float f2_eval(int n2, const float lx[VV],
    const float* __restrict__ lam0, const float4* __restrict__ lam1,
    const float4* __restrict__ pow1, const float4* __restrict__ lam2,
    const float4* __restrict__ pow2)
{
    const float4 L2 = lam2[n2];
    const float4 P2 = pow2[n2];
    const float l2c[VV] = { L2.x, L2.y, L2.z, L2.w };
    const float p2c[VV] = { P2.x, P2.y, P2.z, P2.w };
    float acc = 0.f;
#pragma unroll
    for (int c1 = 0; c1 < VV; ++c1) {
        float f1 = f1_eval(n2 * (VV + 1) + c1, lx, lam0, lam1, pow1);
        acc = fmaf(l2c[c1] * __builtin_amdgcn_exp2f(p2c[c1] * lx[c1]), f1, acc);
    }
    return acc + f1_eval(n2 * (VV + 1) + VV, lx, lam0, lam1, pow1);
}

__device__ __forceinline__ float f3_eval(int n3, const float lx[VV],
    const float* __restrict__ lam0, const float4* __restrict__ lam1,
    const float4* __restrict__ pow1, const float4* __restrict__ lam2,
    const float4* __restrict__ pow2, const float4* __restrict__ lam3,
    const float4* __restrict__ pow3)
{
    const float4 L3 = lam3[n3];
    const float4 P3 = pow3[n3];
    const float l3c[VV] = { L3.x, L3.y, L3.z, L3.w };
    const float p3c[VV] = { P3.x, P3.y, P3.z, P3.w };
    float acc = 0.f;
#pragma unroll
    for (int c2 = 0; c2 < VV; ++c2) {
        float f2 = f2_eval(n3 * (VV + 1) + c2, lx, lam0, lam1, pow1, lam2, pow2);
        acc = fmaf(l3c[c2] * __builtin_amdgcn_exp2f(p3c[c2] * lx[c2]), f2, acc);
    }
    return acc + f2_eval(n3 * (VV + 1) + VV, lx, lam0, lam1, pow1, lam2, pow2);
}

__global__ __launch_bounds__(256) void nested_formula_r6(
    const float4* __restrict__ x,      // (B, 4)
    const float*  __restrict__ lam0,   // (125,)
    const float4* __restrict__ lam1,   // (125,4)
    const float4* __restrict__ pow1,   // (125,4)
    const float4* __restrict__ lam2,   // (25,4)
    const float4* __restrict__ pow2,   // (25,4)
    const float4* __restrict__ lam3,   // (5,4)
    const float4* __restrict__ pow3,   // (5,4)
    const float4* __restrict__ lam4,   // (1,4)
    const float4* __restrict__ pow4,   // (1,4)
    float* __restrict__ out,           // (B,) pre-zeroed
    int B)
{
    const int r = blockIdx.y;                          // 0..3, uniform
    const int b = blockIdx.x * blockDim.x + threadIdx.x;
    if (b >= B) return;

    float4 xv = x[b];
    float lx[VV] = { __builtin_amdgcn_logf(xv.x), __builtin_amdgcn_logf(xv.y),
                     __builtin_amdgcn_logf(xv.z), __builtin_amdgcn_logf(xv.w) };
    const float lxr = (r == 0) ? lx[0] : (r == 1) ? lx[1]
                    : (r == 2) ? lx[2] : lx[3];

    const float4 L4 = lam4[0], P4 = pow4[0];
    const float l4c[VV] = { L4.x, L4.y, L4.z, L4.w };
    const float p4c[VV] = { P4.x, P4.y, P4.z, P4.w };
    const float l4r = (r == 0) ? l4c[0] : (r == 1) ? l4c[1]
                    : (r == 2) ? l4c[2] : l4c[3];
    const float p4r = (r == 0) ? p4c[0] : (r == 1) ? p4c[1]
                    : (r == 2) ? p4c[2] : p4c[3];

    // A_r: depth-3 subtree r, weighted by the depth-4 edge
    float f3 = f3_eval(r, lx, lam0, lam1, pow1, lam2, pow2, lam3, pow3);
    float partial = l4r * __builtin_amdgcn_exp2f(p4r * lxr) * f3;

    // B_r: depth-2 node (20+r) = child r of depth-3 node 4
    {
        const float4 L3 = lam3[4], P3 = pow3[4];
        const float l3c[VV] = { L3.x, L3.y, L3.z, L3.w };
        const float p3c[VV] = { P3.x, P3.y, P3.z, P3.w };
        const float l3r = (r == 0) ? l3c[0] : (r == 1) ? l3c[1]
                        : (r == 2) ? l3c[2] : l3c[3];
        const float p3r = (r == 0) ? p3c[0] : (r == 1) ? p3c[1]
                        : (r == 2) ? p3c[2] : p3c[3];
        float f2 = f2_eval(4 * (VV + 1) + r, lx, lam0, lam1, pow1, lam2, pow2);
        partial = fmaf(l3r * __builtin_amdgcn_exp2f(p3r * lxr), f2, partial);
    }

    // C_r: depth-1 node (120+r) = child r of depth-2 node 24
    {
        const float4 L2 = lam2[24], P2 = pow2[24];
        const float l2c[VV] = { L2.x, L2.y, L2.z, L2.w };
        const float p2c[VV] = { P2.x, P2.y, P2.z, P2.w };
        const float l2r = (r == 0) ? l2c[0] : (r == 1) ? l2c[1]
                        : (r == 2) ? l2c[2] : l2c[3];
        const float p2r = (r == 0) ? p2c[0] : (r == 1) ? p2c[1]
                        : (r == 2) ? p2c[2] : p2c[3];
        float f1 = f1_eval(24 * (VV + 1) + r, lx, lam0, lam1, pow1);
        partial = fmaf(l2r * __builtin_amdgcn_exp2f(p2r * lxr), f1, partial);
    }

    // last chain: f1(124) contributes raw; assign to r==0 (uniform branch)
    if (r == 0)
        partial += f1_eval(24 * (VV + 1) + VV, lx, lam0, lam1, pow1);

    unsafeAtomicAdd(&out[b], partial);
}

extern "C" void kernel_launch(void* const* d_in, const int* in_sizes, int n_in,
                              void* d_out, int out_size, void* d_ws, size_t ws_size,
                              hipStream_t stream) {
    const float4* x    = (const float4*)d_in[0];
    const float*  lam0 = (const float*)d_in[1];
    const float4* lam1 = (const float4*)d_in[2];
    const float4* pow1 = (const float4*)d_in[3];
    const float4* lam2 = (const float4*)d_in[4];
    const float4* pow2 = (const float4*)d_in[5];
    const float4* lam3 = (const float4*)d_in[6];
    const float4* pow3 = (const float4*)d_in[7];
    const float4* lam4 = (const float4*)d_in[8];
    const float4* pow4 = (const float4*)d_in[9];
    float* out = (float*)d_out;

    int B = in_sizes[0] / 4;  // x is (B, 4)
    hipMemsetAsync(out, 0, (size_t)B * sizeof(float), stream);

    dim3 block(256, 1, 1);
    dim3 grid((B + 255) / 256, 4, 1);   // 512 x 4 blocks, 8192 waves
    nested_formula_r6<<<grid, block, 0, stream>>>(
        x, lam0, lam1, pow1, lam2, pow2, lam3, pow3, lam4, pow4, out, B);
}

// Round 7
// 82.630 us; speedup vs baseline: 1.1671x; 1.1671x over previous
//
#include <hip/hip_runtime.h>

// NestedFormula: DEPTH=4, V=4, B=131072. n1=125, n2=25, n3=5, n4=1.
//
// R7: 5-way split by depth-3 subtree (r = threadIdx>>6, wave-uniform ->
// zero divergence, params stay on the scalar pipe), all splits in one
// 320-thread block, E=2 batch elements per thread:
//  - two independent dep chains per thread hide exp/fma latency in-wave
//  - every scalar param load is shared by 2 elements (halves SMEM)
//  - LDS reduce (2.5KB) replaces R4's global atomics + memset dispatch
// f4 = sum_{r<4} lam4[r]*x_r^pow4[r] * f3(r)  +  f3(4)   (balanced ~125
// exps per split). 1024 blocks x 5 waves = 5120 waves, body ~9KB (I$ ok).

#define VV 4

__device__ __forceinline__ void f1_eval2(int n1,
    const float lxA[VV], const float lxB[VV],
    const float* __restrict__ lam0, const float* __restrict__ lam1,
    const float* __restrict__ pow1, float& fA, float& fB)
{
    float a = lam0[n1], b = a;
#pragma unroll
    for (int v = 0; v < VV; ++v) {
        const float p = pow1[n1 * VV + v];
        const float l = lam1[n1 * VV + v];
        a = fmaf(l, __builtin_amdgcn_exp2f(p * lxA[v]), a);
        b = fmaf(l, __builtin_amdgcn_exp2f(p * lxB[v]), b);
    }
    fA = a; fB = b;
}

__device__ __forceinline__ void f2_eval2(int n2,
    const float lxA[VV], const float lxB[VV],
    const float* __restrict__ lam0, const float* __restrict__ lam1,
    const float* __restrict__ pow1, const float* __restrict__ lam2,
    const float* __restrict__ pow2, float& fA, float& fB)
{
    float accA = 0.f, accB = 0.f;
#pragma unroll
    for (int c1 = 0; c1 < VV; ++c1) {
        float f1A, f1B;
        f1_eval2(n2 * (VV + 1) + c1, lxA, lxB, lam0, lam1, pow1, f1A, f1B);
        const float l = lam2[n2 * VV + c1];
        const float p = pow2[n2 * VV + c1];
        accA = fmaf(l * __builtin_amdgcn_exp2f(p * lxA[c1]), f1A, accA);
        accB = fmaf(l * __builtin_amdgcn_exp2f(p * lxB[c1]), f1B, accB);
    }
    float lA, lB;
    f1_eval2(n2 * (VV + 1) + VV, lxA, lxB, lam0, lam1, pow1, lA, lB);
    fA = accA + lA; fB = accB + lB;
}

__device__ __forceinline__ void f3_eval2(int n3,
    const float lxA[VV], const float lxB[VV],
    const float* __restrict__ lam0, const float* __restrict__ lam1,
    const float* __restrict__ pow1, const float* __restrict__ lam2,
    const float* __restrict__ pow2, const float* __restrict__ lam3,
    const float* __restrict__ pow3, float& fA, float& fB)
{
    float accA = 0.f, accB = 0.f;
#pragma unroll
    for (int c2 = 0; c2 < VV; ++c2) {
        float f2A, f2B;
        f2_eval2(n3 * (VV + 1) + c2, lxA, lxB, lam0, lam1, pow1, lam2, pow2,
                 f2A, f2B);
        const float l = lam3[n3 * VV + c2];
        const float p = pow3[n3 * VV + c2];
        accA = fmaf(l * __builtin_amdgcn_exp2f(p * lxA[c2]), f2A, accA);
        accB = fmaf(l * __builtin_amdgcn_exp2f(p * lxB[c2]), f2B, accB);
    }
    float lA, lB;
    f2_eval2(n3 * (VV + 1) + VV, lxA, lxB, lam0, lam1, pow1, lam2, pow2, lA, lB);
    fA = accA + lA; fB = accB + lB;
}

__global__ __launch_bounds__(320) void nested_formula_r7(
    const float4* __restrict__ x,      // (B, 4)
    const float*  __restrict__ lam0,   // (125,)
    const float*  __restrict__ lam1,   // (125,4)
    const float*  __restrict__ pow1,   // (125,4)
    const float*  __restrict__ lam2,   // (25,4)
    const float*  __restrict__ pow2,   // (25,4)
    const float*  __restrict__ lam3,   // (5,4)
    const float*  __restrict__ pow3,   // (5,4)
    const float*  __restrict__ lam4,   // (1,4)
    const float*  __restrict__ pow4,   // (1,4)
    float* __restrict__ out,           // (B,)
    int B)
{
    const int lane = threadIdx.x & 63;
    const int r    = threadIdx.x >> 6;           // 0..4, wave-uniform
    const int b0   = blockIdx.x * 128 + lane;    // elements b0 and b0+64
    const int b1   = b0 + 64;

    __shared__ float red[5][128];                // 2.5KB; 2-way alias = free

    const float4 xa = x[min(b0, B - 1)];
    const float4 xb = x[min(b1, B - 1)];
    const float lxA[VV] = { __builtin_amdgcn_logf(xa.x), __builtin_amdgcn_logf(xa.y),
                            __builtin_amdgcn_logf(xa.z), __builtin_amdgcn_logf(xa.w) };
    const float lxB[VV] = { __builtin_amdgcn_logf(xb.x), __builtin_amdgcn_logf(xb.y),
                            __builtin_amdgcn_logf(xb.z), __builtin_amdgcn_logf(xb.w) };

    float f3A, f3B;
    f3_eval2(r, lxA, lxB, lam0, lam1, pow1, lam2, pow2, lam3, pow3, f3A, f3B);

    float pA, pB;
    if (r < 4) {                                  // uniform branch
        const float l4 = lam4[r];
        const float p4 = pow4[r];
        const float lxrA = (r == 0) ? lxA[0] : (r == 1) ? lxA[1]
                         : (r == 2) ? lxA[2] : lxA[3];
        const float lxrB = (r == 0) ? lxB[0] : (r == 1) ? lxB[1]
                         : (r == 2) ? lxB[2] : lxB[3];
        pA = l4 * __builtin_amdgcn_exp2f(p4 * lxrA) * f3A;
        pB = l4 * __builtin_amdgcn_exp2f(p4 * lxrB) * f3B;
    } else {                                      // last_subformula: weight 1
        pA = f3A;
        pB = f3B;
    }

    red[r][lane]      = pA;
    red[r][lane + 64] = pB;
    __syncthreads();

    if (r == 0) {
        float sA = ((red[0][lane] + red[1][lane]) +
                    (red[2][lane] + red[3][lane])) + red[4][lane];
        float sB = ((red[0][lane + 64] + red[1][lane + 64]) +
                    (red[2][lane + 64] + red[3][lane + 64])) + red[4][lane + 64];
        if (b0 < B) out[b0] = sA;
        if (b1 < B) out[b1] = sB;
    }
}

extern "C" void kernel_launch(void* const* d_in, const int* in_sizes, int n_in,
                              void* d_out, int out_size, void* d_ws, size_t ws_size,
                              hipStream_t stream) {
    const float4* x    = (const float4*)d_in[0];
    const float*  lam0 = (const float*)d_in[1];
    const float*  lam1 = (const float*)d_in[2];
    const float*  pow1 = (const float*)d_in[3];
    const float*  lam2 = (const float*)d_in[4];
    const float*  pow2 = (const float*)d_in[5];
    const float*  lam3 = (const float*)d_in[6];
    const float*  pow3 = (const float*)d_in[7];
    const float*  lam4 = (const float*)d_in[8];
    const float*  pow4 = (const float*)d_in[9];
    float* out = (float*)d_out;

    int B = in_sizes[0] / 4;  // x is (B, 4)
    dim3 block(320, 1, 1);                 // 5 waves: one per depth-3 subtree
    dim3 grid((B + 127) / 128, 1, 1);      // 1024 blocks at B=131072
    nested_formula_r7<<<grid, block, 0, stream>>>(
        x, lam0, lam1, pow1, lam2, pow2, lam3, pow3, lam4, pow4, out, B);
}